// Round 17
// baseline (178.033 us; speedup 1.0000x reference)
//
#include <hip/hip_runtime.h>
#include <hip/hip_fp16.h>
#include <string.h>

namespace {
constexpr int kN = 50000;
constexpr int kD = 256;
constexpr int kPos = 32;
constexpr int kNeg = 20;
constexpr float kEps = 1e-15f;
constexpr int kSlots = kPos / 4 + kNeg / 4;  // 13 per 16-lane group
constexpr int kCompactBlocks = (kN + 255) / 256;   // 196
constexpr int kConvertBlocks = kN * kD / 8 / 256;  // 6250
constexpr int kRowBlocks = (kN + 3) / 4;           // 12500

typedef float floatx2 __attribute__((ext_vector_type(2)));

#if __has_builtin(__builtin_amdgcn_cvt_pk_f32_fp8)
constexpr bool kHwCvtPk = true;
#else
constexpr bool kHwCvtPk = false;
#endif
// software-decode fallback yields value*2^-8, so own must be pre-scaled by 256
constexpr float kOwnScale = kHwCvtPk ? 1.f : 256.f;

// ---------- fp8 e4m3fn encode ----------
__device__ __forceinline__ uint enc1(float x) {
    const __half hh = __float2half(x * 0.00390625f);  // x * 2^-8, HW RNE
    unsigned short t;
    memcpy(&t, &hh, 2);
    const uint s = ((uint)t >> 8) & 0x80u;
    uint mag = (uint)t & 0x7fffu;
    mag = mag + 0x3fu + ((mag >> 7) & 1u);  // RNE 10->3 bit mantissa
    uint u = mag >> 7;
    if (u > 0x7eu) u = 0x7eu;
    return s | u;
}

__device__ __forceinline__ uint enc4(const float4 a) {
#if __has_builtin(__builtin_amdgcn_cvt_pk_fp8_f32)
    int u = __builtin_amdgcn_cvt_pk_fp8_f32(a.x, a.y, 0, false);    // bytes 0,1
    u = __builtin_amdgcn_cvt_pk_fp8_f32(a.z, a.w, u, true);         // bytes 2,3
    return (uint)u;
#else
    return enc1(a.x) | (enc1(a.y) << 8) | (enc1(a.z) << 16) | (enc1(a.w) << 24);
#endif
}

__device__ __forceinline__ float dec_h(uint h) {
    __half hh;
    const unsigned short t = (unsigned short)h;
    memcpy(&hh, &t, 2);
    return __half2float(hh);
}

// PACKED decode+accumulate: 4 e4m3 bytes against packed own pairs o01,o23.
// v_cvt_pk_f32_fp8 yields packed float2; floatx2 accumulate -> v_pk_fma_f32
// (8 pk-fma/slot vs 16 scalar fma). Round-16 measured: VALUBusy 64->56%.
__device__ __forceinline__ void dq4p(uint u, const floatx2 o01, const floatx2 o23,
                                     floatx2& d2) {
#if __has_builtin(__builtin_amdgcn_cvt_pk_f32_fp8)
    const floatx2 lo = __builtin_amdgcn_cvt_pk_f32_fp8((int)u, false);  // bytes 0,1
    const floatx2 hi = __builtin_amdgcn_cvt_pk_f32_fp8((int)u, true);   // bytes 2,3
    d2 += lo * o01;  // -ffp-contract: v_pk_fma_f32
    d2 += hi * o23;
#else
    floatx2 lo, hi;
    lo.x = dec_h(((u << 8) & 0x8000u) | ((u << 7) & 0x3f80u));
    lo.y = dec_h((u & 0x8000u) | ((u >> 1) & 0x3f80u));
    hi.x = dec_h(((u >> 8) & 0x8000u) | ((u >> 9) & 0x3f80u));
    hi.y = dec_h(((u >> 16) & 0x8000u) | ((u >> 17) & 0x3f80u));
    d2 += lo * o01;
    d2 += hi * o23;
#endif
}

// ---------- fused prep: compaction + flat fp8 convert (round-14 verified) ---
__global__ __launch_bounds__(256) void prep_kernel(const float* __restrict__ emb,
                                                   uint* __restrict__ tbl,
                                                   const int* __restrict__ rmask,
                                                   int* __restrict__ list,
                                                   float* __restrict__ acc) {
    const int bid = blockIdx.x;
    if (bid < kCompactBlocks) {
        const int n = bid * 256 + threadIdx.x;
        if (n < kN && rmask[n]) {
            const int p = atomicAdd(reinterpret_cast<unsigned*>(&acc[2]), 1u);
            list[p] = n;
        }
    } else {
        const size_t i = ((size_t)(bid - kCompactBlocks) * 256 + threadIdx.x) * 8;
        const float4* src = reinterpret_cast<const float4*>(emb + i);
        uint2 o;
        o.x = enc4(src[0]);
        o.y = enc4(src[1]);
        reinterpret_cast<uint2*>(tbl)[i / 8] = o;
    }
}

// One wave per ACTIVE row; round-14 structure (depth-4 rotating prefetch,
// plain blocksum store = atomic-storm fix, 93.5->55.9us) + pk-fma decode.
// ROUND-16 LESSON: pk-fma alone pushed VGPR 56->68, crossing the 64-VGPR
// occupancy cliff (8->7 waves/SIMD, Occupancy 34.9->28.4%) and netting -3%.
// __launch_bounds__(256, 8) = 8 waves/EU -> allocator VGPR cap 64: keeps the
// VALU cut AND full occupancy. Materialization check: VGPR<=64, Occ ~35%.
// NOTE (round-15): MFMA/global_load_lds/device-ticket variants all killed the
// MI355X container (3/3); this file intentionally stays plain-HIP.
__global__ __launch_bounds__(256, 8) void row_loss_fp8(
    const float* __restrict__ emb,
    const uchar* __restrict__ tblb,
    const int* __restrict__ nbr,
    const int* __restrict__ nbrm,
    const int* __restrict__ neg,
    const int* __restrict__ list,
    const float* __restrict__ acc,
    float* __restrict__ blocksum) {
    __shared__ float s_num[4];
    const int wave = threadIdx.x >> 6;
    const int lane = threadIdx.x & 63;
    const int g = lane >> 4;
    const int t = lane & 15;
    const uint lane_off = (uint)t * 16u;

    const int cnt_active = reinterpret_cast<const int*>(acc)[2];
    const int i = blockIdx.x * 4 + wave;
    float num = 0.f;

    if (i < cnt_active) {  // wave-uniform
        const int n = list[i];

        // own row fp32 (exact), elems 16t..16t+15, packed in pairs for pk-fma
        const float4* erow = reinterpret_cast<const float4*>(emb + (size_t)n * kD);
        floatx2 own2[8];
#pragma unroll
        for (int j = 0; j < 4; ++j) {
            const float4 f = erow[4 * t + j];
            own2[2 * j + 0].x = f.x * kOwnScale;
            own2[2 * j + 0].y = f.y * kOwnScale;
            own2[2 * j + 1].x = f.z * kOwnScale;
            own2[2 * j + 1].y = f.w * kOwnScale;
        }

        const int* nrow = nbr + (size_t)n * kPos;
        const int* mrow = nbrm + (size_t)n * kPos;
        const int* grow = neg + (size_t)n * kNeg;

        // preload all offsets + weights
        uint off[kSlots];  // 32-bit byte offsets into the 12.8 MB table
        float w[kPos / 4];
        float cnt = 0.f;
#pragma unroll
        for (int s = 0; s < kPos / 4; ++s) {
            off[s] = ((uint)nrow[s * 4 + g] << 8) + lane_off;
            const float mf = (float)mrow[s * 4 + g];
            w[s] = mf;
            cnt += mf;
        }
#pragma unroll
        for (int s = 0; s < kNeg / 4; ++s)
            off[kPos / 4 + s] = ((uint)grow[s * 4 + g] << 8) + lane_off;

        float pos_sum = 0.f, neg_sum = 0.f;

#define LD(s) (*reinterpret_cast<const uint4*>(tblb + off[s]))
#define DO_SLOT(s, B)                                                       \
    {                                                                       \
        floatx2 d2 = {0.f, 0.f};                                            \
        dq4p(B.x, own2[0], own2[1], d2);                                    \
        dq4p(B.y, own2[2], own2[3], d2);                                    \
        dq4p(B.z, own2[4], own2[5], d2);                                    \
        dq4p(B.w, own2[6], own2[7], d2);                                    \
        float d = d2.x + d2.y;                                              \
        d += __shfl_xor(d, 8);                                              \
        d += __shfl_xor(d, 4);                                              \
        d += __shfl_xor(d, 2);                                              \
        d += __shfl_xor(d, 1);                                              \
        const float sg = 1.f / (1.f + __expf(-d));                          \
        if ((s) < kPos / 4) {                                               \
            pos_sum += -__logf(sg + kEps) * w[(s) & 7];                     \
        } else {                                                            \
            neg_sum += -__logf(1.f - sg + kEps);                            \
        }                                                                   \
    }

        // prologue: 4 gathers in flight
        uint4 b0 = LD(0);
        uint4 b1 = LD(1);
        uint4 b2 = LD(2);
        uint4 b3 = LD(3);
        // steady state: decode oldest, reissue its buffer 4 slots ahead
        DO_SLOT(0, b0); b0 = LD(4);
        DO_SLOT(1, b1); b1 = LD(5);
        DO_SLOT(2, b2); b2 = LD(6);
        DO_SLOT(3, b3); b3 = LD(7);
        DO_SLOT(4, b0); b0 = LD(8);
        DO_SLOT(5, b1); b1 = LD(9);
        DO_SLOT(6, b2); b2 = LD(10);
        DO_SLOT(7, b3); b3 = LD(11);
        DO_SLOT(8, b0); b0 = LD(12);
        // drain tail
        DO_SLOT(9, b1);
        DO_SLOT(10, b2);
        DO_SLOT(11, b3);
        DO_SLOT(12, b0);
#undef LD
#undef DO_SLOT

        // combine the 4 groups (each group's 16 lanes hold identical values)
        pos_sum += __shfl_xor(pos_sum, 16);
        pos_sum += __shfl_xor(pos_sum, 32);
        neg_sum += __shfl_xor(neg_sum, 16);
        neg_sum += __shfl_xor(neg_sum, 32);
        cnt += __shfl_xor(cnt, 16);
        cnt += __shfl_xor(cnt, 32);

        if (cnt > 0.f) num = pos_sum / cnt + neg_sum / (float)kNeg;
        // cnt==0 -> NaN row in reference -> replaced by 0 -> contributes 0
    }

    if (lane == 0) s_num[wave] = num;
    __syncthreads();
    if (threadIdx.x == 0) {
        // plain store per block — NO same-address atomic (round-13 fix)
        blocksum[blockIdx.x] = s_num[0] + s_num[1] + s_num[2] + s_num[3];
    }
}

// ---------- single-block reduction of the 12500 block sums (UNCHANGED) ------
__global__ __launch_bounds__(256) void reduce_kernel(
    const float* __restrict__ blocksum,
    const float* __restrict__ acc,
    float* __restrict__ out) {
    __shared__ float s_sum[4];
    const int lane = threadIdx.x & 63;
    const int wave = threadIdx.x >> 6;
    float v = 0.f;
    for (int i = threadIdx.x; i < kRowBlocks; i += 256) v += blocksum[i];
#pragma unroll
    for (int o = 32; o >= 1; o >>= 1) v += __shfl_xor(v, o);
    if (lane == 0) s_sum[wave] = v;
    __syncthreads();
    if (threadIdx.x == 0) {
        const float tot = s_sum[0] + s_sum[1] + s_sum[2] + s_sum[3];
        out[0] = tot / (float)reinterpret_cast<const int*>(acc)[2];
    }
}

// ---------- fp32 direct fallback (tiny ws; UNCHANGED) ----------
__global__ __launch_bounds__(256) void row_loss_f32(
    const float* __restrict__ emb,
    const int* __restrict__ nbr,
    const int* __restrict__ nbrm,
    const int* __restrict__ neg,
    const int* __restrict__ rmask,
    float* __restrict__ acc) {
    __shared__ float s_num[4];
    __shared__ float s_den[4];
    const int wave = threadIdx.x >> 6;
    const int lane = threadIdx.x & 63;
    const int n = blockIdx.x * 4 + wave;
    const int g = lane >> 4;
    const int t = lane & 15;

    const float4* erow = reinterpret_cast<const float4*>(emb + (size_t)n * kD);
    float4 own4[4];
#pragma unroll
    for (int j = 0; j < 4; ++j) own4[j] = erow[j * 16 + t];

    const int* nrow = nbr + (size_t)n * kPos;
    const int* mrow = nbrm + (size_t)n * kPos;
    const int* grow = neg + (size_t)n * kNeg;

    float pos_sum = 0.f, neg_sum = 0.f, cnt = 0.f;
#pragma unroll
    for (int it = 0; it < kPos / 4; ++it) {
        const int idx = nrow[it * 4 + g];
        const float mf = (float)mrow[it * 4 + g];
        cnt += mf;
        const float4* brow = reinterpret_cast<const float4*>(emb + (size_t)idx * kD);
        float d = 0.f;
#pragma unroll
        for (int j = 0; j < 4; ++j) {
            const float4 b = brow[j * 16 + t];
            const float4 a = own4[j];
            d += a.x * b.x + a.y * b.y + a.z * b.z + a.w * b.w;
        }
        d += __shfl_xor(d, 8);
        d += __shfl_xor(d, 4);
        d += __shfl_xor(d, 2);
        d += __shfl_xor(d, 1);
        const float s = 1.f / (1.f + __expf(-d));
        pos_sum += -__logf(s + kEps) * mf;
    }
#pragma unroll
    for (int it = 0; it < kNeg / 4; ++it) {
        const int idx = grow[it * 4 + g];
        const float4* brow = reinterpret_cast<const float4*>(emb + (size_t)idx * kD);
        float d = 0.f;
#pragma unroll
        for (int j = 0; j < 4; ++j) {
            const float4 b = brow[j * 16 + t];
            const float4 a = own4[j];
            d += a.x * b.x + a.y * b.y + a.z * b.z + a.w * b.w;
        }
        d += __shfl_xor(d, 8);
        d += __shfl_xor(d, 4);
        d += __shfl_xor(d, 2);
        d += __shfl_xor(d, 1);
        const float s = 1.f / (1.f + __expf(-d));
        neg_sum += -__logf(1.f - s + kEps);
    }

    pos_sum += __shfl_xor(pos_sum, 16);
    pos_sum += __shfl_xor(pos_sum, 32);
    neg_sum += __shfl_xor(neg_sum, 16);
    neg_sum += __shfl_xor(neg_sum, 32);
    cnt += __shfl_xor(cnt, 16);
    cnt += __shfl_xor(cnt, 32);

    float num = 0.f;
    if (cnt > 0.f) num = pos_sum / cnt + neg_sum / (float)kNeg;
    const float rmf = (float)rmask[n];

    if (lane == 0) {
        s_num[wave] = num * rmf;
        s_den[wave] = rmf;
    }
    __syncthreads();
    if (threadIdx.x == 0) {
        atomicAdd(&acc[0], s_num[0] + s_num[1] + s_num[2] + s_num[3]);
        atomicAdd(&acc[1], s_den[0] + s_den[1] + s_den[2] + s_den[3]);
    }
}

__global__ void finalize_f32(const float* __restrict__ acc, float* __restrict__ out) {
    out[0] = acc[0] / acc[1];
}
}  // namespace

extern "C" void kernel_launch(void* const* d_in, const int* in_sizes, int n_in,
                              void* d_out, int out_size, void* d_ws, size_t ws_size,
                              hipStream_t stream) {
    const float* emb = (const float*)d_in[0];
    const int* nbr = (const int*)d_in[1];
    const int* nbrm = (const int*)d_in[2];
    const int* neg = (const int*)d_in[3];
    const int* rmask = (const int*)d_in[4];
    float* acc = (float*)d_ws;  // [0]=num, [1]=den, [2]=active count

    const size_t bsum_bytes = (size_t)kRowBlocks * sizeof(float);  // 50 KB
    const size_t tbl_bytes = (size_t)kN * kD;                      // 12.8 MB
    const size_t list_bytes = (size_t)kN * sizeof(int);            // 0.2 MB

    if (ws_size >= 256 + bsum_bytes + tbl_bytes + list_bytes) {
        float* bsum = (float*)((char*)d_ws + 256);
        uint* tbl = (uint*)((char*)d_ws + 256 + bsum_bytes);
        int* list = (int*)((char*)d_ws + 256 + bsum_bytes + tbl_bytes);
        hipMemsetAsync(acc, 0, 4 * sizeof(float), stream);
        prep_kernel<<<kCompactBlocks + kConvertBlocks, 256, 0, stream>>>(
            emb, tbl, rmask, list, acc);
        row_loss_fp8<<<kRowBlocks, 256, 0, stream>>>(emb, (const uchar*)tbl, nbr,
                                                     nbrm, neg, list, acc, bsum);
        reduce_kernel<<<1, 256, 0, stream>>>(bsum, acc, (float*)d_out);
    } else {
        hipMemsetAsync(acc, 0, 2 * sizeof(float), stream);
        row_loss_f32<<<kN / 4, 256, 0, stream>>>(emb, nbr, nbrm, neg, rmask, acc);
        finalize_f32<<<1, 1, 0, stream>>>(acc, (float*)d_out);
    }
}

// Round 18
// 172.136 us; speedup vs baseline: 1.0343x; 1.0343x over previous
//
#include <hip/hip_runtime.h>
#include <hip/hip_fp16.h>
#include <string.h>

namespace {
constexpr int kN = 50000;
constexpr int kD = 256;
constexpr int kPos = 32;
constexpr int kNeg = 20;
constexpr float kEps = 1e-15f;
constexpr int kSlots = kPos / 4 + kNeg / 4;  // 13 per 16-lane group
constexpr int kCompactBlocks = (kN + 255) / 256;   // 196
constexpr int kConvertBlocks = kN * kD / 8 / 256;  // 6250
constexpr int kRowBlocks = (kN + 3) / 4;           // 12500

typedef float floatx2 __attribute__((ext_vector_type(2)));

#if __has_builtin(__builtin_amdgcn_cvt_pk_f32_fp8)
constexpr bool kHwCvtPk = true;
#else
constexpr bool kHwCvtPk = false;
#endif
// software-decode fallback yields value*2^-8, so own must be pre-scaled by 256
constexpr float kOwnScale = kHwCvtPk ? 1.f : 256.f;

// ---------- fp8 e4m3fn encode ----------
__device__ __forceinline__ uint enc1(float x) {
    const __half hh = __float2half(x * 0.00390625f);  // x * 2^-8, HW RNE
    unsigned short t;
    memcpy(&t, &hh, 2);
    const uint s = ((uint)t >> 8) & 0x80u;
    uint mag = (uint)t & 0x7fffu;
    mag = mag + 0x3fu + ((mag >> 7) & 1u);  // RNE 10->3 bit mantissa
    uint u = mag >> 7;
    if (u > 0x7eu) u = 0x7eu;
    return s | u;
}

__device__ __forceinline__ uint enc4(const float4 a) {
#if __has_builtin(__builtin_amdgcn_cvt_pk_fp8_f32)
    int u = __builtin_amdgcn_cvt_pk_fp8_f32(a.x, a.y, 0, false);    // bytes 0,1
    u = __builtin_amdgcn_cvt_pk_fp8_f32(a.z, a.w, u, true);         // bytes 2,3
    return (uint)u;
#else
    return enc1(a.x) | (enc1(a.y) << 8) | (enc1(a.z) << 16) | (enc1(a.w) << 24);
#endif
}

__device__ __forceinline__ float dec_h(uint h) {
    __half hh;
    const unsigned short t = (unsigned short)h;
    memcpy(&hh, &t, 2);
    return __half2float(hh);
}

// Decode 4 packed e4m3 bytes and accumulate dot with o[0..3].
// ROUND-17 FINAL: scalar fmaf decode is the measured optimum. The bracket
// {scalar/VGPR56/Occ35% = 55.9us, pk-fma/VGPR68/Occ28% = 57.5us,
//  pk-fma+lb(256,8)/VGPR32/Occ73% = 60.0us} shows per-wave register budget
// (pipeline depth) beats both VALU-op count and occupancy on this kernel.
__device__ __forceinline__ void dq4(uint u, const float* o, float& d) {
#if __has_builtin(__builtin_amdgcn_cvt_pk_f32_fp8)
    const floatx2 lo = __builtin_amdgcn_cvt_pk_f32_fp8((int)u, false);  // bytes 0,1
    const floatx2 hi = __builtin_amdgcn_cvt_pk_f32_fp8((int)u, true);   // bytes 2,3
    d = fmaf(lo.x, o[0], d);
    d = fmaf(lo.y, o[1], d);
    d = fmaf(hi.x, o[2], d);
    d = fmaf(hi.y, o[3], d);
#else
    const float v0 = dec_h(((u << 8) & 0x8000u) | ((u << 7) & 0x3f80u));
    const float v1 = dec_h((u & 0x8000u) | ((u >> 1) & 0x3f80u));
    const float v2 = dec_h(((u >> 8) & 0x8000u) | ((u >> 9) & 0x3f80u));
    const float v3 = dec_h(((u >> 16) & 0x8000u) | ((u >> 17) & 0x3f80u));
    d = fmaf(v0, o[0], d);
    d = fmaf(v1, o[1], d);
    d = fmaf(v2, o[2], d);
    d = fmaf(v3, o[3], d);
#endif
}

// ---------- fused prep: compaction + flat fp8 convert ----------
__global__ __launch_bounds__(256) void prep_kernel(const float* __restrict__ emb,
                                                   uint* __restrict__ tbl,
                                                   const int* __restrict__ rmask,
                                                   int* __restrict__ list,
                                                   float* __restrict__ acc) {
    const int bid = blockIdx.x;
    if (bid < kCompactBlocks) {
        const int n = bid * 256 + threadIdx.x;
        if (n < kN && rmask[n]) {
            const int p = atomicAdd(reinterpret_cast<unsigned*>(&acc[2]), 1u);
            list[p] = n;
        }
    } else {
        const size_t i = ((size_t)(bid - kCompactBlocks) * 256 + threadIdx.x) * 8;
        const float4* src = reinterpret_cast<const float4*>(emb + i);
        uint2 o;
        o.x = enc4(src[0]);
        o.y = enc4(src[1]);
        reinterpret_cast<uint2*>(tbl)[i / 8] = o;
    }
}

// One wave per ACTIVE row; round-14 verified body (session best: row_loss
// 55.9us, e2e 171.8us). Depth-4 rotating prefetch (named buffers), scalar
// dq4 decode, and the ATOMIC-STORM FIX: the invariant ~94us "pin" of rounds
// 0-10 was 6250 same-address atomicAdd(out) serialized at ~32cy each (round
// 13 diagnosis: finish_loss 83.6us at 7.7% VALU). Tail is a plain store to
// blocksum[bid]; reduce_kernel sums the 12500 values.
// NOTE: MFMA / global_load_lds / device-ticket variants all killed the
// MI355X container (3/3) — this file intentionally stays plain-HIP.
__global__ __launch_bounds__(256) void row_loss_fp8(
    const float* __restrict__ emb,
    const uchar* __restrict__ tblb,
    const int* __restrict__ nbr,
    const int* __restrict__ nbrm,
    const int* __restrict__ neg,
    const int* __restrict__ list,
    const float* __restrict__ acc,
    float* __restrict__ blocksum) {
    __shared__ float s_num[4];
    const int wave = threadIdx.x >> 6;
    const int lane = threadIdx.x & 63;
    const int g = lane >> 4;
    const int t = lane & 15;
    const uint lane_off = (uint)t * 16u;

    const int cnt_active = reinterpret_cast<const int*>(acc)[2];
    const int i = blockIdx.x * 4 + wave;
    float num = 0.f;

    if (i < cnt_active) {  // wave-uniform
        const int n = list[i];

        // own row fp32 (exact), elems 16t..16t+15
        const float4* erow = reinterpret_cast<const float4*>(emb + (size_t)n * kD);
        float own[16];
#pragma unroll
        for (int j = 0; j < 4; ++j) {
            const float4 f = erow[4 * t + j];
            own[4 * j + 0] = f.x * kOwnScale;
            own[4 * j + 1] = f.y * kOwnScale;
            own[4 * j + 2] = f.z * kOwnScale;
            own[4 * j + 3] = f.w * kOwnScale;
        }

        const int* nrow = nbr + (size_t)n * kPos;
        const int* mrow = nbrm + (size_t)n * kPos;
        const int* grow = neg + (size_t)n * kNeg;

        // preload all offsets + weights
        uint off[kSlots];  // 32-bit byte offsets into the 12.8 MB table
        float w[kPos / 4];
        float cnt = 0.f;
#pragma unroll
        for (int s = 0; s < kPos / 4; ++s) {
            off[s] = ((uint)nrow[s * 4 + g] << 8) + lane_off;
            const float mf = (float)mrow[s * 4 + g];
            w[s] = mf;
            cnt += mf;
        }
#pragma unroll
        for (int s = 0; s < kNeg / 4; ++s)
            off[kPos / 4 + s] = ((uint)grow[s * 4 + g] << 8) + lane_off;

        float pos_sum = 0.f, neg_sum = 0.f;

#define LD(s) (*reinterpret_cast<const uint4*>(tblb + off[s]))
#define DO_SLOT(s, B)                                                       \
    {                                                                       \
        float d = 0.f;                                                      \
        dq4(B.x, own + 0, d);                                               \
        dq4(B.y, own + 4, d);                                               \
        dq4(B.z, own + 8, d);                                               \
        dq4(B.w, own + 12, d);                                              \
        d += __shfl_xor(d, 8);                                              \
        d += __shfl_xor(d, 4);                                              \
        d += __shfl_xor(d, 2);                                              \
        d += __shfl_xor(d, 1);                                              \
        const float sg = 1.f / (1.f + __expf(-d));                          \
        if ((s) < kPos / 4) {                                               \
            pos_sum += -__logf(sg + kEps) * w[(s) & 7];                     \
        } else {                                                            \
            neg_sum += -__logf(1.f - sg + kEps);                            \
        }                                                                   \
    }

        // prologue: 4 gathers in flight
        uint4 b0 = LD(0);
        uint4 b1 = LD(1);
        uint4 b2 = LD(2);
        uint4 b3 = LD(3);
        // steady state: decode oldest, reissue its buffer 4 slots ahead
        DO_SLOT(0, b0); b0 = LD(4);
        DO_SLOT(1, b1); b1 = LD(5);
        DO_SLOT(2, b2); b2 = LD(6);
        DO_SLOT(3, b3); b3 = LD(7);
        DO_SLOT(4, b0); b0 = LD(8);
        DO_SLOT(5, b1); b1 = LD(9);
        DO_SLOT(6, b2); b2 = LD(10);
        DO_SLOT(7, b3); b3 = LD(11);
        DO_SLOT(8, b0); b0 = LD(12);
        // drain tail
        DO_SLOT(9, b1);
        DO_SLOT(10, b2);
        DO_SLOT(11, b3);
        DO_SLOT(12, b0);
#undef LD
#undef DO_SLOT

        // combine the 4 groups (each group's 16 lanes hold identical values)
        pos_sum += __shfl_xor(pos_sum, 16);
        pos_sum += __shfl_xor(pos_sum, 32);
        neg_sum += __shfl_xor(neg_sum, 16);
        neg_sum += __shfl_xor(neg_sum, 32);
        cnt += __shfl_xor(cnt, 16);
        cnt += __shfl_xor(cnt, 32);

        if (cnt > 0.f) num = pos_sum / cnt + neg_sum / (float)kNeg;
        // cnt==0 -> NaN row in reference -> replaced by 0 -> contributes 0
    }

    if (lane == 0) s_num[wave] = num;
    __syncthreads();
    if (threadIdx.x == 0) {
        // plain store per block — NO same-address atomic (round-13 fix)
        blocksum[blockIdx.x] = s_num[0] + s_num[1] + s_num[2] + s_num[3];
    }
}

// ---------- single-block reduction of the 12500 block sums ----------
__global__ __launch_bounds__(256) void reduce_kernel(
    const float* __restrict__ blocksum,
    const float* __restrict__ acc,
    float* __restrict__ out) {
    __shared__ float s_sum[4];
    const int lane = threadIdx.x & 63;
    const int wave = threadIdx.x >> 6;
    float v = 0.f;
    for (int i = threadIdx.x; i < kRowBlocks; i += 256) v += blocksum[i];
#pragma unroll
    for (int o = 32; o >= 1; o >>= 1) v += __shfl_xor(v, o);
    if (lane == 0) s_sum[wave] = v;
    __syncthreads();
    if (threadIdx.x == 0) {
        const float tot = s_sum[0] + s_sum[1] + s_sum[2] + s_sum[3];
        out[0] = tot / (float)reinterpret_cast<const int*>(acc)[2];
    }
}

// ---------- fp32 direct fallback (tiny ws; UNCHANGED) ----------
__global__ __launch_bounds__(256) void row_loss_f32(
    const float* __restrict__ emb,
    const int* __restrict__ nbr,
    const int* __restrict__ nbrm,
    const int* __restrict__ neg,
    const int* __restrict__ rmask,
    float* __restrict__ acc) {
    __shared__ float s_num[4];
    __shared__ float s_den[4];
    const int wave = threadIdx.x >> 6;
    const int lane = threadIdx.x & 63;
    const int n = blockIdx.x * 4 + wave;
    const int g = lane >> 4;
    const int t = lane & 15;

    const float4* erow = reinterpret_cast<const float4*>(emb + (size_t)n * kD);
    float4 own4[4];
#pragma unroll
    for (int j = 0; j < 4; ++j) own4[j] = erow[j * 16 + t];

    const int* nrow = nbr + (size_t)n * kPos;
    const int* mrow = nbrm + (size_t)n * kPos;
    const int* grow = neg + (size_t)n * kNeg;

    float pos_sum = 0.f, neg_sum = 0.f, cnt = 0.f;
#pragma unroll
    for (int it = 0; it < kPos / 4; ++it) {
        const int idx = nrow[it * 4 + g];
        const float mf = (float)mrow[it * 4 + g];
        cnt += mf;
        const float4* brow = reinterpret_cast<const float4*>(emb + (size_t)idx * kD);
        float d = 0.f;
#pragma unroll
        for (int j = 0; j < 4; ++j) {
            const float4 b = brow[j * 16 + t];
            const float4 a = own4[j];
            d += a.x * b.x + a.y * b.y + a.z * b.z + a.w * b.w;
        }
        d += __shfl_xor(d, 8);
        d += __shfl_xor(d, 4);
        d += __shfl_xor(d, 2);
        d += __shfl_xor(d, 1);
        const float s = 1.f / (1.f + __expf(-d));
        pos_sum += -__logf(s + kEps) * mf;
    }
#pragma unroll
    for (int it = 0; it < kNeg / 4; ++it) {
        const int idx = grow[it * 4 + g];
        const float4* brow = reinterpret_cast<const float4*>(emb + (size_t)idx * kD);
        float d = 0.f;
#pragma unroll
        for (int j = 0; j < 4; ++j) {
            const float4 b = brow[j * 16 + t];
            const float4 a = own4[j];
            d += a.x * b.x + a.y * b.y + a.z * b.z + a.w * b.w;
        }
        d += __shfl_xor(d, 8);
        d += __shfl_xor(d, 4);
        d += __shfl_xor(d, 2);
        d += __shfl_xor(d, 1);
        const float s = 1.f / (1.f + __expf(-d));
        neg_sum += -__logf(1.f - s + kEps);
    }

    pos_sum += __shfl_xor(pos_sum, 16);
    pos_sum += __shfl_xor(pos_sum, 32);
    neg_sum += __shfl_xor(neg_sum, 16);
    neg_sum += __shfl_xor(neg_sum, 32);
    cnt += __shfl_xor(cnt, 16);
    cnt += __shfl_xor(cnt, 32);

    float num = 0.f;
    if (cnt > 0.f) num = pos_sum / cnt + neg_sum / (float)kNeg;
    const float rmf = (float)rmask[n];

    if (lane == 0) {
        s_num[wave] = num * rmf;
        s_den[wave] = rmf;
    }
    __syncthreads();
    if (threadIdx.x == 0) {
        atomicAdd(&acc[0], s_num[0] + s_num[1] + s_num[2] + s_num[3]);
        atomicAdd(&acc[1], s_den[0] + s_den[1] + s_den[2] + s_den[3]);
    }
}

__global__ void finalize_f32(const float* __restrict__ acc, float* __restrict__ out) {
    out[0] = acc[0] / acc[1];
}
}  // namespace

extern "C" void kernel_launch(void* const* d_in, const int* in_sizes, int n_in,
                              void* d_out, int out_size, void* d_ws, size_t ws_size,
                              hipStream_t stream) {
    const float* emb = (const float*)d_in[0];
    const int* nbr = (const int*)d_in[1];
    const int* nbrm = (const int*)d_in[2];
    const int* neg = (const int*)d_in[3];
    const int* rmask = (const int*)d_in[4];
    float* acc = (float*)d_ws;  // [0]=num, [1]=den, [2]=active count

    const size_t bsum_bytes = (size_t)kRowBlocks * sizeof(float);  // 50 KB
    const size_t tbl_bytes = (size_t)kN * kD;                      // 12.8 MB
    const size_t list_bytes = (size_t)kN * sizeof(int);            // 0.2 MB

    if (ws_size >= 256 + bsum_bytes + tbl_bytes + list_bytes) {
        float* bsum = (float*)((char*)d_ws + 256);
        uint* tbl = (uint*)((char*)d_ws + 256 + bsum_bytes);
        int* list = (int*)((char*)d_ws + 256 + bsum_bytes + tbl_bytes);
        hipMemsetAsync(acc, 0, 4 * sizeof(float), stream);
        prep_kernel<<<kCompactBlocks + kConvertBlocks, 256, 0, stream>>>(
            emb, tbl, rmask, list, acc);
        row_loss_fp8<<<kRowBlocks, 256, 0, stream>>>(emb, (const uchar*)tbl, nbr,
                                                     nbrm, neg, list, acc, bsum);
        reduce_kernel<<<1, 256, 0, stream>>>(bsum, acc, (float*)d_out);
    } else {
        hipMemsetAsync(acc, 0, 2 * sizeof(float), stream);
        row_loss_f32<<<kN / 4, 256, 0, stream>>>(emb, nbr, nbrm, neg, rmask, acc);
        finalize_f32<<<1, 1, 0, stream>>>(acc, (float*)d_out);
    }
}